// Round 8
// baseline (694.602 us; speedup 1.0000x reference)
//
#include <hip/hip_runtime.h>

#define BB    16
#define TT    64
#define F0    8
#define NN    100
#define NEX   15
#define F1    32
#define F2    64
#define HRD   64
#define OUTD  5
#define BT    (BB*TT)        // 1024
#define MROWS (BT*NN)        // 102400
#define NK    14             // stored diffusion steps k'=1..14 (z15 unused)
#define ZELEMS  ((size_t)BT*NK*NN*F0)     // 11,468,800 floats (45.9 MB)
#define Y1ELEMS ((size_t)BT*6*NN*F1)      // 19,660,800 floats (78.6 MB)
#define Y2ELEMS ((size_t)MROWS*128)       // 13,107,200 floats (52.4 MB)

// ===========================================================================
// Head: 4 diagonal chains per block share one LDS-staged S[b,t] per t-step.
// Double-buffered Sld/zl -> ONE barrier per step; S[t+1] loads issued before
// compute. Stores z_k' (k'=1..14) as [bt][k'-1][n][8f] float4s.
// ===========================================================================
__global__ __launch_bounds__(512) void head_chain(
    const float* __restrict__ x, const float* __restrict__ S,
    float* __restrict__ zbuf) {
  __shared__ float Sld[2][NN * NN];    // 2 x 40 KB
  __shared__ float zl[2][4 * NN * F0]; // 2 x 12.8 KB

  const int blk = blockIdx.x;
  const int b   = blk >> 4;
  const int g   = blk & 15;
  const int tb  = 1 + 4 * g;
  const int te  = min(tb + 16, TT - 1);      // last step: chain3 k=13
  const int tid = threadIdx.x;
  const int m   = tid & 127;
  const int c2  = (tid >> 7) & 1;
  const int f0b = (tid >> 8) * 4;

  auto act = [&](int T, int dst) {
    const int c = T - tb;
    if (c >= 0 && c < 4 && T <= TT - 1 && (c & 1) == c2 && m < NN) {
#pragma unroll
      for (int j = 0; j < 4; ++j)
        zl[dst][c * (NN * F0) + m * F0 + f0b + j] =
            x[((size_t)(b * TT + T - 1) * F0 + f0b + j) * NN + m];
    }
  };

  {
    const float4* Sg = (const float4*)(S + (size_t)(b * TT + tb) * NN * NN);
    float4 R[5];
#pragma unroll
    for (int i = 0; i < 5; ++i) {
      int idx = tid + i * 512; if (idx > 2499) idx = 2499;
      R[i] = Sg[idx];
    }
#pragma unroll
    for (int i = 0; i < 5; ++i) {
      const int idx = tid + i * 512;
      if (idx < 2500) *(float4*)&Sld[0][idx * 4] = R[i];
    }
  }
  act(tb, 0);
  __syncthreads();

  int p = 0;
  for (int t = tb; t <= te; ++t, p ^= 1) {
    const bool more = (t < te);
    float4 Rn[5];
    if (more) {
      const float4* Sg =
          (const float4*)(S + (size_t)(b * TT + t + 1) * NN * NN);
#pragma unroll
      for (int i = 0; i < 5; ++i) {
        int idx = tid + i * 512; if (idx > 2499) idx = 2499;
        Rn[i] = Sg[idx];
      }
    }

    const int t0a = tb + c2;
    const int t0b = tb + c2 + 2;
    const bool a0 = (t >= t0a) && (t <= t0a + 13);
    const bool a1 = (t >= t0b) && (t <= t0b + 13) && (t0b <= TT - 1);

    float acc0[4] = {0.f, 0.f, 0.f, 0.f};
    float acc1[4] = {0.f, 0.f, 0.f, 0.f};
    if (m < NN) {
      const float* Sc = Sld[p];
      const float* zA = &zl[p][c2 * (NN * F0) + f0b];
      const float* zB = &zl[p][(c2 + 2) * (NN * F0) + f0b];
      if (a0 && a1) {
#pragma unroll 10
        for (int n = 0; n < NN; ++n) {
          const float s = Sc[n * NN + m];
          const float4 z0 = *(const float4*)&zA[n * F0];
          const float4 z1 = *(const float4*)&zB[n * F0];
          acc0[0] += z0.x * s; acc0[1] += z0.y * s;
          acc0[2] += z0.z * s; acc0[3] += z0.w * s;
          acc1[0] += z1.x * s; acc1[1] += z1.y * s;
          acc1[2] += z1.z * s; acc1[3] += z1.w * s;
        }
      } else if (a0) {
#pragma unroll 10
        for (int n = 0; n < NN; ++n) {
          const float s = Sc[n * NN + m];
          const float4 z0 = *(const float4*)&zA[n * F0];
          acc0[0] += z0.x * s; acc0[1] += z0.y * s;
          acc0[2] += z0.z * s; acc0[3] += z0.w * s;
        }
      } else if (a1) {
#pragma unroll 10
        for (int n = 0; n < NN; ++n) {
          const float s = Sc[n * NN + m];
          const float4 z1 = *(const float4*)&zB[n * F0];
          acc1[0] += z1.x * s; acc1[1] += z1.y * s;
          acc1[2] += z1.z * s; acc1[3] += z1.w * s;
        }
      }
    }

    if (m < NN) {
      if (a0) {
        *(float4*)&zl[p ^ 1][c2 * (NN * F0) + m * F0 + f0b] =
            make_float4(acc0[0], acc0[1], acc0[2], acc0[3]);
        const int k = t - t0a;               // 0..13
        *(float4*)&zbuf[(((size_t)(b * TT + t) * NK + k) * NN + m) * F0 + f0b] =
            make_float4(acc0[0], acc0[1], acc0[2], acc0[3]);
      }
      if (a1) {
        *(float4*)&zl[p ^ 1][(c2 + 2) * (NN * F0) + m * F0 + f0b] =
            make_float4(acc1[0], acc1[1], acc1[2], acc1[3]);
        const int k = t - t0b;
        *(float4*)&zbuf[(((size_t)(b * TT + t) * NK + k) * NN + m) * F0 + f0b] =
            make_float4(acc1[0], acc1[1], acc1[2], acc1[3]);
      }
    }
    act(t + 1, p ^ 1);
    if (more) {
#pragma unroll
      for (int i = 0; i < 5; ++i) {
        const int idx = tid + i * 512;
        if (idx < 2500) *(float4*)&Sld[p ^ 1][idx * 4] = Rn[i];
      }
    }
    __syncthreads();
  }
}

// ===========================================================================
// conv1: thread-per-row, co chunk of 8 (gridDim.y=4). k-outer over z
// positions: k=0 from x (8 dwords), k=1..14 as 2x float4 from zbuf,
// guarded by k<=t. Writes y1 [bt][p][n][32co] as 2 float4 per p.
// ===========================================================================
__global__ __launch_bounds__(256) void conv1_k(
    const float* __restrict__ x, const float* __restrict__ zbuf,
    const float* __restrict__ w1, const float* __restrict__ b1,
    float* __restrict__ y1g) {
  const int row = blockIdx.x * 256 + threadIdx.x;
  const int bt  = row / NN;
  const int n   = row - bt * NN;
  const int t   = bt & (TT - 1);
  const int c0  = blockIdx.y * 8;

  float acc[8][12];
#pragma unroll
  for (int j = 0; j < 8; ++j) {
    const float bias = b1[c0 + j];
#pragma unroll
    for (int l = 0; l < 12; ++l) acc[j][l] = bias;
  }

  // k = 0 (from x): contributes only (l=0, kk=0)
  {
    float zf[8];
#pragma unroll
    for (int ci = 0; ci < 8; ++ci)
      zf[ci] = x[((size_t)bt * F0 + ci) * NN + n];
#pragma unroll
    for (int j = 0; j < 8; ++j)
#pragma unroll
      for (int ci = 0; ci < 8; ++ci)
        acc[j][0] += zf[ci] * w1[((c0 + j) * F0 + ci) * 4 + 0];
  }

  // k = 1..14 from zbuf
#pragma unroll
  for (int k = 1; k < 15; ++k) {
    if (k <= t) {
      const float4* zp =
          (const float4*)(zbuf + (((size_t)bt * NK + (k - 1)) * NN + n) * F0);
      const float4 za = zp[0], zb = zp[1];
      const float zf[8] = {za.x, za.y, za.z, za.w, zb.x, zb.y, zb.z, zb.w};
#pragma unroll
      for (int j = 0; j < 8; ++j)
#pragma unroll
        for (int ci = 0; ci < 8; ++ci)
#pragma unroll
          for (int kk = 0; kk < 4; ++kk) {
            const int l = k - kk;
            if (l >= 0 && l < 12)
              acc[j][l] += zf[ci] * w1[((c0 + j) * F0 + ci) * 4 + kk];
          }
    }
  }

  // ReLU + pool2 -> y1[bt][p][n][32], co c0..c0+8 as two float4
#pragma unroll
  for (int p = 0; p < 6; ++p) {
    float r[8];
#pragma unroll
    for (int j = 0; j < 8; ++j)
      r[j] = fmaxf(fmaxf(acc[j][2 * p], acc[j][2 * p + 1]), 0.f);
    float* yp = y1g + (((size_t)bt * 6 + p) * NN + n) * F1 + c0;
    *(float4*)&yp[0] = make_float4(r[0], r[1], r[2], r[3]);
    *(float4*)&yp[4] = make_float4(r[4], r[5], r[6], r[7]);
  }
}

// ===========================================================================
// conv2: thread-per-row, co chunk of 16 (gridDim.y=4). l-outer: 8 float4
// loads of y1[bt][l][n][:32] per l, static-unrolled taps into acc[16][4].
// Writes y2 [row][128], d = 2*cc..2*cc+32 as 8 float4.
// ===========================================================================
__global__ __launch_bounds__(256) void conv2_k(
    const float* __restrict__ y1g,
    const float* __restrict__ w2, const float* __restrict__ b2,
    float* __restrict__ y2g) {
  const int row = blockIdx.x * 256 + threadIdx.x;
  const int bt  = row / NN;
  const int n   = row - bt * NN;
  const int cc  = blockIdx.y * 16;

  float acc[16][4];
#pragma unroll
  for (int j = 0; j < 16; ++j) {
    const float bb = b2[cc + j];
#pragma unroll
    for (int l = 0; l < 4; ++l) acc[j][l] = bb;
  }

#pragma unroll
  for (int l = 0; l < 6; ++l) {
    const float4* yp =
        (const float4*)(y1g + (((size_t)bt * 6 + l) * NN + n) * F1);
    float4 y4[8];
#pragma unroll
    for (int i = 0; i < 8; ++i) y4[i] = yp[i];
    const float* yv = (const float*)y4;
#pragma unroll
    for (int j = 0; j < 16; ++j)
#pragma unroll
      for (int ci = 0; ci < 32; ++ci)
#pragma unroll
        for (int kk = 0; kk < 3; ++kk) {
          const int pos = l - kk;
          if (pos >= 0 && pos < 4)
            acc[j][pos] += yv[ci] * w2[((cc + j) * F1 + ci) * 3 + kk];
        }
  }

  // ReLU + pool2 -> y2[row][2*cc .. 2*cc+32) as 8 float4
  float* yo = y2g + (size_t)row * 128 + 2 * cc;
#pragma unroll
  for (int j = 0; j < 16; j += 2) {
    const float a0 = fmaxf(fmaxf(acc[j][0], acc[j][1]), 0.f);
    const float a1 = fmaxf(fmaxf(acc[j][2], acc[j][3]), 0.f);
    const float b0 = fmaxf(fmaxf(acc[j + 1][0], acc[j + 1][1]), 0.f);
    const float b1v = fmaxf(fmaxf(acc[j + 1][2], acc[j + 1][3]), 0.f);
    *(float4*)&yo[2 * j] = make_float4(a0, a1, b0, b1v);
  }
}

// ===========================================================================
// fc: thread-per-row. v[128] as 32 float4 loads; fc1 j-loop with contiguous
// uniform fw1 rows (s_loads); fc2 folded into the j-loop.
// ===========================================================================
__global__ __launch_bounds__(256) void fc_k(
    const float* __restrict__ y2g,
    const float* __restrict__ fw1, const float* __restrict__ fb1,
    const float* __restrict__ fw2, const float* __restrict__ fb2,
    float* __restrict__ out) {
  const int row = blockIdx.x * 256 + threadIdx.x;
  const int bt  = row / NN;
  const int n   = row - bt * NN;

  float4 v4[32];
  const float4* yp = (const float4*)(y2g + (size_t)row * 128);
#pragma unroll
  for (int i = 0; i < 32; ++i) v4[i] = yp[i];
  const float* v = (const float*)v4;

  float o[OUTD];
#pragma unroll
  for (int q = 0; q < OUTD; ++q) o[q] = fb2[q];

  for (int j = 0; j < HRD; ++j) {
    const float* wr = fw1 + j * 128;     // uniform, contiguous -> s_loads
    float s0 = 0.f, s1 = 0.f, s2 = 0.f, s3 = 0.f;
#pragma unroll
    for (int d = 0; d < 128; d += 4) {
      s0 += v[d + 0] * wr[d + 0];
      s1 += v[d + 1] * wr[d + 1];
      s2 += v[d + 2] * wr[d + 2];
      s3 += v[d + 3] * wr[d + 3];
    }
    const float h = fmaxf((s0 + s1) + (s2 + s3) + fb1[j], 0.f);
#pragma unroll
    for (int q = 0; q < OUTD; ++q) o[q] += h * fw2[q * HRD + j];
  }
#pragma unroll
  for (int q = 0; q < OUTD; ++q)
    out[((size_t)bt * OUTD + q) * NN + n] = o[q];
}

// ===========================================================================
extern "C" void kernel_launch(void* const* d_in, const int* in_sizes, int n_in,
                              void* d_out, int out_size, void* d_ws,
                              size_t ws_size, hipStream_t stream) {
  const float* x   = (const float*)d_in[0];
  const float* S   = (const float*)d_in[1];
  const float* w1  = (const float*)d_in[2];
  const float* b1  = (const float*)d_in[3];
  const float* w2  = (const float*)d_in[4];
  const float* b2  = (const float*)d_in[5];
  const float* fw1 = (const float*)d_in[6];
  const float* fb1 = (const float*)d_in[7];
  const float* fw2 = (const float*)d_in[8];
  const float* fb2 = (const float*)d_in[9];

  float* zbuf = (float*)d_ws;                 // 45.9 MB
  float* y1g  = zbuf + ZELEMS;                // 78.6 MB
  float* y2g  = y1g + Y1ELEMS;                // 52.4 MB  (total 176.9 MB)
  float* outp = (float*)d_out;

  head_chain<<<BB * 16, 512, 0, stream>>>(x, S, zbuf);
  conv1_k<<<dim3(MROWS / 256, 4), 256, 0, stream>>>(x, zbuf, w1, b1, y1g);
  conv2_k<<<dim3(MROWS / 256, 4), 256, 0, stream>>>(y1g, w2, b2, y2g);
  fc_k<<<MROWS / 256, 256, 0, stream>>>(y2g, fw1, fb1, fw2, fb2, outp);
}

// Round 9
// 287.094 us; speedup vs baseline: 2.4194x; 2.4194x over previous
//
#include <hip/hip_runtime.h>

#define BB    16
#define TT    64
#define F0    8
#define NN    100
#define NEX   15
#define F1    32
#define F2    64
#define HRD   64
#define OUTD  5
#define BT    (BB*TT)        // 1024
#define MROWS (BT*NN)        // 102400
#define NK    14             // stored diffusion steps k'=1..14 (z15 unused)
#define ZELEMS  ((size_t)BT*F0*NK*NN)     // 11,468,800 floats (45.9 MB)
#define Y1ELEMS ((size_t)BT*F1*6*NN)      // 19,660,800 floats (78.6 MB)
#define Y2ELEMS ((size_t)BT*128*NN)       // 13,107,200 floats (52.4 MB)

// ===========================================================================
// Head: 4 diagonal chains per block share one LDS-staged S[b,t] per t-step.
// Double-buffered Sld/zl -> ONE barrier per step; S[t+1] loads issued before
// compute. Stores z_k' (k'=1..14) scalar-coalesced as [bt][f][k'-1][n].
// ===========================================================================
__global__ __launch_bounds__(512) void head_chain(
    const float* __restrict__ x, const float* __restrict__ S,
    float* __restrict__ zbuf) {
  __shared__ float Sld[2][NN * NN];    // 2 x 40 KB
  __shared__ float zl[2][4 * NN * F0]; // 2 x 12.8 KB

  const int blk = blockIdx.x;
  const int b   = blk >> 4;
  const int g   = blk & 15;
  const int tb  = 1 + 4 * g;
  const int te  = min(tb + 16, TT - 1);      // last step: chain3 k=13
  const int tid = threadIdx.x;
  const int m   = tid & 127;
  const int c2  = (tid >> 7) & 1;
  const int f0b = (tid >> 8) * 4;

  auto act = [&](int T, int dst) {
    const int c = T - tb;
    if (c >= 0 && c < 4 && T <= TT - 1 && (c & 1) == c2 && m < NN) {
#pragma unroll
      for (int j = 0; j < 4; ++j)
        zl[dst][c * (NN * F0) + m * F0 + f0b + j] =
            x[((size_t)(b * TT + T - 1) * F0 + f0b + j) * NN + m];
    }
  };

  {
    const float4* Sg = (const float4*)(S + (size_t)(b * TT + tb) * NN * NN);
    float4 R[5];
#pragma unroll
    for (int i = 0; i < 5; ++i) {
      int idx = tid + i * 512; if (idx > 2499) idx = 2499;
      R[i] = Sg[idx];
    }
#pragma unroll
    for (int i = 0; i < 5; ++i) {
      const int idx = tid + i * 512;
      if (idx < 2500) *(float4*)&Sld[0][idx * 4] = R[i];
    }
  }
  act(tb, 0);
  __syncthreads();

  int p = 0;
  for (int t = tb; t <= te; ++t, p ^= 1) {
    const bool more = (t < te);
    float4 Rn[5];
    if (more) {
      const float4* Sg =
          (const float4*)(S + (size_t)(b * TT + t + 1) * NN * NN);
#pragma unroll
      for (int i = 0; i < 5; ++i) {
        int idx = tid + i * 512; if (idx > 2499) idx = 2499;
        Rn[i] = Sg[idx];
      }
    }

    const int t0a = tb + c2;
    const int t0b = tb + c2 + 2;
    const bool a0 = (t >= t0a) && (t <= t0a + 13);
    const bool a1 = (t >= t0b) && (t <= t0b + 13) && (t0b <= TT - 1);

    float acc0[4] = {0.f, 0.f, 0.f, 0.f};
    float acc1[4] = {0.f, 0.f, 0.f, 0.f};
    if (m < NN) {
      const float* Sc = Sld[p];
      const float* zA = &zl[p][c2 * (NN * F0) + f0b];
      const float* zB = &zl[p][(c2 + 2) * (NN * F0) + f0b];
      if (a0 && a1) {
#pragma unroll 10
        for (int n = 0; n < NN; ++n) {
          const float s = Sc[n * NN + m];
          const float4 z0 = *(const float4*)&zA[n * F0];
          const float4 z1 = *(const float4*)&zB[n * F0];
          acc0[0] += z0.x * s; acc0[1] += z0.y * s;
          acc0[2] += z0.z * s; acc0[3] += z0.w * s;
          acc1[0] += z1.x * s; acc1[1] += z1.y * s;
          acc1[2] += z1.z * s; acc1[3] += z1.w * s;
        }
      } else if (a0) {
#pragma unroll 10
        for (int n = 0; n < NN; ++n) {
          const float s = Sc[n * NN + m];
          const float4 z0 = *(const float4*)&zA[n * F0];
          acc0[0] += z0.x * s; acc0[1] += z0.y * s;
          acc0[2] += z0.z * s; acc0[3] += z0.w * s;
        }
      } else if (a1) {
#pragma unroll 10
        for (int n = 0; n < NN; ++n) {
          const float s = Sc[n * NN + m];
          const float4 z1 = *(const float4*)&zB[n * F0];
          acc1[0] += z1.x * s; acc1[1] += z1.y * s;
          acc1[2] += z1.z * s; acc1[3] += z1.w * s;
        }
      }
    }

    if (m < NN) {
      if (a0) {
        *(float4*)&zl[p ^ 1][c2 * (NN * F0) + m * F0 + f0b] =
            make_float4(acc0[0], acc0[1], acc0[2], acc0[3]);
        const int k = t - t0a;               // 0..13
#pragma unroll
        for (int j = 0; j < 4; ++j)
          zbuf[(((size_t)(b * TT + t) * F0 + f0b + j) * NK + k) * NN + m] =
              acc0[j];
      }
      if (a1) {
        *(float4*)&zl[p ^ 1][(c2 + 2) * (NN * F0) + m * F0 + f0b] =
            make_float4(acc1[0], acc1[1], acc1[2], acc1[3]);
        const int k = t - t0b;
#pragma unroll
        for (int j = 0; j < 4; ++j)
          zbuf[(((size_t)(b * TT + t) * F0 + f0b + j) * NK + k) * NN + m] =
              acc1[j];
      }
    }
    act(t + 1, p ^ 1);
    if (more) {
#pragma unroll
      for (int i = 0; i < 5; ++i) {
        const int idx = tid + i * 512;
        if (idx < 2500) *(float4*)&Sld[p ^ 1][idx * 4] = Rn[i];
      }
    }
    __syncthreads();
  }
}

// ===========================================================================
// conv1: thread-per-row, co chunk of 8 (gridDim.y=4). ROLLED ci loop
// (#pragma unroll 1 — R8 proved full unroll = I$ thrash). All loads
// lane-coalesced dwords; weights wave-uniform s_loads.
// Writes y1 [bt][co][p][n].
// ===========================================================================
__global__ __launch_bounds__(256) void conv1_k(
    const float* __restrict__ x, const float* __restrict__ zbuf,
    const float* __restrict__ w1, const float* __restrict__ b1,
    float* __restrict__ y1g) {
  const int row = blockIdx.x * 256 + threadIdx.x;
  const int bt  = row / NN;
  const int n   = row - bt * NN;
  const int t   = bt & (TT - 1);
  const int c0  = blockIdx.y * 8;

  float acc[8][12];
#pragma unroll
  for (int j = 0; j < 8; ++j) {
    const float bias = b1[c0 + j];
#pragma unroll
    for (int l = 0; l < 12; ++l) acc[j][l] = bias;
  }

#pragma unroll 1
  for (int ci = 0; ci < F0; ++ci) {
    float zv[15];
    zv[0] = x[((size_t)bt * F0 + ci) * NN + n];
#pragma unroll
    for (int k = 1; k < 15; ++k)
      zv[k] = (k <= t)
          ? zbuf[(((size_t)bt * F0 + ci) * NK + (k - 1)) * NN + n]
          : 0.f;
#pragma unroll
    for (int j = 0; j < 8; ++j)
#pragma unroll
      for (int kk = 0; kk < 4; ++kk) {
        const float w = w1[((c0 + j) * F0 + ci) * 4 + kk];   // uniform
#pragma unroll
        for (int l = 0; l < 12; ++l) acc[j][l] += zv[l + kk] * w;
      }
  }

#pragma unroll
  for (int j = 0; j < 8; ++j)
#pragma unroll
    for (int p = 0; p < 6; ++p)
      y1g[((size_t)bt * (F1 * 6) + (c0 + j) * 6 + p) * NN + n] =
          fmaxf(fmaxf(acc[j][2 * p], acc[j][2 * p + 1]), 0.f);
}

// ===========================================================================
// conv2: thread-per-row, co chunk of 16 (gridDim.y=4). ROLLED ci loop
// (32 iters, ~2KB body). Writes y2 [bt][d=128][n].
// ===========================================================================
__global__ __launch_bounds__(256) void conv2_k(
    const float* __restrict__ y1g,
    const float* __restrict__ w2, const float* __restrict__ b2,
    float* __restrict__ y2g) {
  const int row = blockIdx.x * 256 + threadIdx.x;
  const int bt  = row / NN;
  const int n   = row - bt * NN;
  const int cc  = blockIdx.y * 16;

  float acc[16][4];
#pragma unroll
  for (int j = 0; j < 16; ++j) {
    const float bb = b2[cc + j];
#pragma unroll
    for (int l = 0; l < 4; ++l) acc[j][l] = bb;
  }

#pragma unroll 1
  for (int ci = 0; ci < F1; ++ci) {
    float yv[6];
#pragma unroll
    for (int l = 0; l < 6; ++l)
      yv[l] = y1g[((size_t)bt * (F1 * 6) + ci * 6 + l) * NN + n];
#pragma unroll
    for (int j = 0; j < 16; ++j)
#pragma unroll
      for (int kk = 0; kk < 3; ++kk) {
        const float w = w2[((cc + j) * F1 + ci) * 3 + kk];   // uniform
#pragma unroll
        for (int l = 0; l < 4; ++l) acc[j][l] += yv[l + kk] * w;
      }
  }

#pragma unroll
  for (int j = 0; j < 16; ++j) {
    y2g[((size_t)bt * 128 + (cc + j) * 2 + 0) * NN + n] =
        fmaxf(fmaxf(acc[j][0], acc[j][1]), 0.f);
    y2g[((size_t)bt * 128 + (cc + j) * 2 + 1) * NN + n] =
        fmaxf(fmaxf(acc[j][2], acc[j][3]), 0.f);
  }
}

// ===========================================================================
// fc: thread-per-row. v[128] coalesced dword loads; fc1 j-loop (rolled, 64
// iters) with contiguous uniform fw1 rows (s_load_x16 batches); fc2 folded.
// ===========================================================================
__global__ __launch_bounds__(256) void fc_k(
    const float* __restrict__ y2g,
    const float* __restrict__ fw1, const float* __restrict__ fb1,
    const float* __restrict__ fw2, const float* __restrict__ fb2,
    float* __restrict__ out) {
  const int row = blockIdx.x * 256 + threadIdx.x;
  const int bt  = row / NN;
  const int n   = row - bt * NN;
  const float* yi = y2g + (size_t)bt * 128 * NN + n;

  float v[128];
#pragma unroll
  for (int d = 0; d < 128; ++d) v[d] = yi[(size_t)d * NN];

  float o[OUTD];
#pragma unroll
  for (int q = 0; q < OUTD; ++q) o[q] = fb2[q];

#pragma unroll 1
  for (int j = 0; j < HRD; ++j) {
    const float* wr = fw1 + j * 128;     // uniform, contiguous -> s_loads
    float s0 = 0.f, s1 = 0.f, s2 = 0.f, s3 = 0.f;
#pragma unroll
    for (int d = 0; d < 128; d += 4) {
      s0 += v[d + 0] * wr[d + 0];
      s1 += v[d + 1] * wr[d + 1];
      s2 += v[d + 2] * wr[d + 2];
      s3 += v[d + 3] * wr[d + 3];
    }
    const float h = fmaxf((s0 + s1) + (s2 + s3) + fb1[j], 0.f);
#pragma unroll
    for (int q = 0; q < OUTD; ++q) o[q] += h * fw2[q * HRD + j];
  }
#pragma unroll
  for (int q = 0; q < OUTD; ++q)
    out[((size_t)bt * OUTD + q) * NN + n] = o[q];
}

// ===========================================================================
extern "C" void kernel_launch(void* const* d_in, const int* in_sizes, int n_in,
                              void* d_out, int out_size, void* d_ws,
                              size_t ws_size, hipStream_t stream) {
  const float* x   = (const float*)d_in[0];
  const float* S   = (const float*)d_in[1];
  const float* w1  = (const float*)d_in[2];
  const float* b1  = (const float*)d_in[3];
  const float* w2  = (const float*)d_in[4];
  const float* b2  = (const float*)d_in[5];
  const float* fw1 = (const float*)d_in[6];
  const float* fb1 = (const float*)d_in[7];
  const float* fw2 = (const float*)d_in[8];
  const float* fb2 = (const float*)d_in[9];

  float* zbuf = (float*)d_ws;                 // 45.9 MB
  float* y1g  = zbuf + ZELEMS;                // 78.6 MB
  float* y2g  = y1g + Y1ELEMS;                // 52.4 MB  (total 176.9 MB)
  float* outp = (float*)d_out;

  head_chain<<<BB * 16, 512, 0, stream>>>(x, S, zbuf);
  conv1_k<<<dim3(MROWS / 256, 4), 256, 0, stream>>>(x, zbuf, w1, b1, y1g);
  conv2_k<<<dim3(MROWS / 256, 4), 256, 0, stream>>>(y1g, w2, b2, y2g);
  fc_k<<<MROWS / 256, 256, 0, stream>>>(y2g, fw1, fb1, fw2, fb2, outp);
}